// Round 5
// baseline (1241.801 us; speedup 1.0000x reference)
//
#include <hip/hip_runtime.h>

#define N_NODES 100000
#define N_EDGES 1600000
#define NGRAPHS 256
#define BN_EPS 1e-5f
#define NBUK ((N_NODES + 511) >> 9)           // 196 buckets of 512 dst nodes
#define BIN_EPB 2048                          // edges per binning block
#define BIN_BLOCKS ((N_EDGES + BIN_EPB - 1) / BIN_EPB)  // 782

// ---- helpers ----------------------------------------------------------------

__device__ __forceinline__ unsigned f2ord(float f) {
  unsigned u = __float_as_uint(f);
  return (u & 0x80000000u) ? ~u : (u | 0x80000000u);
}

__device__ __forceinline__ float ord2f(unsigned u) {
  unsigned bits = (u & 0x80000000u) ? (u ^ 0x80000000u) : ~u;
  return __uint_as_float(bits);
}

__device__ __forceinline__ unsigned short f2bf(float f) {   // RNE f32 -> bf16
  unsigned u = __float_as_uint(f);
  unsigned r = u + 0x7FFFu + ((u >> 16) & 1u);
  return (unsigned short)(r >> 16);
}

__device__ __forceinline__ float bf2f(unsigned short b) {
  return __uint_as_float(((unsigned)b) << 16);
}

// Detect whether edge_index is int64 (high dwords all zero) or int32.
__global__ void detect_i64(const unsigned* __restrict__ ei, int* __restrict__ flag) {
  if (blockIdx.x == 0 && threadIdx.x == 0) {
    int f = 1;
    for (int i = 1; i < 64; i += 2) {
      if (ei[i] != 0u) { f = 0; break; }
    }
    *flag = f;
  }
}

__device__ __forceinline__ int load_idx(const void* p, const int* flag, long long i) {
  return (*flag) ? (int)((const long long*)p)[i] : ((const int*)p)[i];
}

// ---- f32 -> bf16 table conversion -------------------------------------------

__global__ __launch_bounds__(256) void to_bf16(const float4* __restrict__ in,
                                               ushort4* __restrict__ out, int n4) {
  int i = blockIdx.x * 256 + threadIdx.x;
  if (i >= n4) return;
  float4 v = in[i];
  ushort4 o;
  o.x = f2bf(v.x); o.y = f2bf(v.y); o.z = f2bf(v.z); o.w = f2bf(v.w);
  out[i] = o;
}

// ---- CSR build (bucketed counting sort) -------------------------------------

__global__ __launch_bounds__(256) void bucket_hist(const void* __restrict__ eiPtr,
                                                   const int* __restrict__ flag,
                                                   int* __restrict__ bucketCount) {
  __shared__ int cnt[NBUK];
  const int tid = threadIdx.x;
  for (int i = tid; i < NBUK; i += 256) cnt[i] = 0;
  __syncthreads();
  const long long chunk0 = (long long)blockIdx.x * BIN_EPB;
  const bool i64 = (*flag != 0);
  #pragma unroll
  for (int j = 0; j < 8; ++j) {
    long long e = chunk0 + j * 256 + tid;
    if (e < N_EDGES) {
      int d = i64 ? (int)((const long long*)eiPtr)[N_EDGES + e]
                  : ((const int*)eiPtr)[N_EDGES + e];
      atomicAdd(&cnt[d >> 9], 1);
    }
  }
  __syncthreads();
  for (int b = tid; b < NBUK; b += 256) {
    int c = cnt[b];
    if (c) atomicAdd(&bucketCount[b], c);
  }
}

__global__ void bucket_scan(const int* __restrict__ bucketCount,
                            int* __restrict__ bucketBase,
                            int* __restrict__ bucketCursor,
                            int* __restrict__ rowPtr) {
  __shared__ int lds[256];
  const int tid = threadIdx.x;
  lds[tid] = (tid < NBUK) ? bucketCount[tid] : 0;
  __syncthreads();
  int own = lds[tid];
  for (int off = 1; off < 256; off <<= 1) {
    int t = (tid >= off) ? lds[tid - off] : 0;
    __syncthreads();
    lds[tid] += t;
    __syncthreads();
  }
  int excl = lds[tid] - own;
  if (tid < NBUK) { bucketBase[tid] = excl; bucketCursor[tid] = excl; }
  if (tid == 0) { bucketBase[NBUK] = N_EDGES; rowPtr[N_NODES] = N_EDGES; }
}

// Bin edges by dst>>9 into bucket-grouped tmp. Packed: x = src | (localdst<<18).
__global__ __launch_bounds__(256) void binpass(const void* __restrict__ eiPtr,
                                               const int* __restrict__ flag,
                                               const float* __restrict__ ew,
                                               int* __restrict__ bucketCursor,
                                               int2* __restrict__ tmp) {
  __shared__ int cnt[NBUK];
  __shared__ int base[NBUK];
  const int tid = threadIdx.x;
  const long long chunk0 = (long long)blockIdx.x * BIN_EPB;
  for (int i = tid; i < NBUK; i += 256) cnt[i] = 0;
  __syncthreads();
  int pk[8], wb[8], rk[8], bk[8];
  const bool i64 = (*flag != 0);
  #pragma unroll
  for (int j = 0; j < 8; ++j) {
    long long e = chunk0 + j * 256 + tid;
    rk[j] = -1;
    if (e < N_EDGES) {
      int s, d;
      if (i64) {
        const long long* ei = (const long long*)eiPtr;
        s = (int)ei[e]; d = (int)ei[N_EDGES + e];
      } else {
        const int* ei = (const int*)eiPtr;
        s = ei[e]; d = ei[N_EDGES + e];
      }
      wb[j] = __float_as_int(ew[e]);
      bk[j] = d >> 9;
      pk[j] = s | ((d & 511) << 18);
      rk[j] = atomicAdd(&cnt[bk[j]], 1);
    }
  }
  __syncthreads();
  for (int b = tid; b < NBUK; b += 256) {
    int c = cnt[b];
    base[b] = c ? atomicAdd(&bucketCursor[b], c) : 0;
  }
  __syncthreads();
  #pragma unroll
  for (int j = 0; j < 8; ++j) {
    if (rk[j] >= 0) {
      int2 r; r.x = pk[j]; r.y = wb[j];
      tmp[base[bk[j]] + rk[j]] = r;
    }
  }
}

// One block per bucket: local hist(512) + LDS scan -> rowPtr slice, then
// scatter within the bucket's L2-hot CSR window.
__global__ __launch_bounds__(256) void place2(const int2* __restrict__ tmp,
                                              const int* __restrict__ bucketBase,
                                              int* __restrict__ rowPtr,
                                              int2* __restrict__ csrSW) {
  __shared__ int cnt[512];
  __shared__ int sc[256];
  __shared__ int cur[512];
  const int b = blockIdx.x;
  const int tid = threadIdx.x;
  const int beg = bucketBase[b];
  const int end = bucketBase[b + 1];
  cnt[tid] = 0; cnt[tid + 256] = 0;
  __syncthreads();
  for (int i = beg + tid; i < end; i += 256) {
    atomicAdd(&cnt[(tmp[i].x >> 18) & 511], 1);
  }
  __syncthreads();
  int c0 = cnt[2 * tid], c1 = cnt[2 * tid + 1];
  int pairSum = c0 + c1;
  sc[tid] = pairSum;
  __syncthreads();
  for (int off = 1; off < 256; off <<= 1) {
    int t = (tid >= off) ? sc[tid - off] : 0;
    __syncthreads();
    sc[tid] += t;
    __syncthreads();
  }
  int exclPair = sc[tid] - pairSum;
  int base0 = beg + exclPair;
  int base1 = base0 + c0;
  int g0 = (b << 9) + 2 * tid;
  if (g0 < N_NODES)     rowPtr[g0]     = base0;
  if (g0 + 1 < N_NODES) rowPtr[g0 + 1] = base1;
  cur[2 * tid] = base0;
  cur[2 * tid + 1] = base1;
  __syncthreads();
  for (int i = beg + tid; i < end; i += 256) {
    int2 e = tmp[i];
    int pos = atomicAdd(&cur[(e.x >> 18) & 511], 1);
    int2 r; r.x = e.x & 0x3FFFF; r.y = e.y;
    csrSW[pos] = r;
  }
}

// ---- fused layer: pull (bf16 gather) -> LDS -> 64x64 GEMM -> epilogue -------
// POOL=false: write bf16 table (relu opt). POOL=true: bias + segment-max pool.

template<bool POOL, bool RELU>
__global__ __launch_bounds__(256) void fused_layer(
    const unsigned short* __restrict__ T,     // bf16 table [N][64]
    const int* __restrict__ rowPtr,
    const int2* __restrict__ csrSW,
    const float* __restrict__ W,
    const float* __restrict__ bias,
    unsigned short* __restrict__ Tout,        // POOL=false
    const void* __restrict__ bPtr,            // POOL=true: sorted batch ids
    const int* __restrict__ flag,
    unsigned* __restrict__ pooled) {          // POOL=true
  __shared__ float At[64][68];
  __shared__ float Wt[64][68];                // Wt[k][c]
  const int tid = threadIdx.x;
  const int lane = tid & 63;
  const int wv = tid >> 6;
  const int rowBase = blockIdx.x * 64;

  // stage W as Wt[k][c] (row k contiguous over c)
  for (int i = tid; i < 4096; i += 256) Wt[i >> 6][i & 63] = W[i];

  // pull phase: wave wv aggregates nodes rowBase + wv*16 + i, lane = feature
  for (int i = 0; i < 16; ++i) {
    int n = rowBase + wv * 16 + i;
    float acc = 0.f;
    if (n < N_NODES) {
      int beg = rowPtr[n], end = rowPtr[n + 1];
      for (int base = beg; base < end; base += 64) {
        int m = min(64, end - base);
        int idx = base + (lane < m ? lane : m - 1);
        int2 meta = csrSW[idx];
        int src = meta.x;
        float w = __int_as_float(meta.y);
        int k = 0;
        for (; k + 8 <= m; k += 8) {
          float v[8], wv8[8];
          #pragma unroll
          for (int j = 0; j < 8; ++j) {
            int s = __shfl(src, k + j);
            wv8[j] = __shfl(w, k + j);
            v[j] = bf2f(T[(size_t)s * 64 + lane]);
          }
          #pragma unroll
          for (int j = 0; j < 8; ++j) acc += wv8[j] * v[j];
        }
        for (; k < m; ++k) {
          int s = __shfl(src, k);
          float ww = __shfl(w, k);
          acc += ww * bf2f(T[(size_t)s * 64 + lane]);
        }
      }
    }
    At[wv * 16 + i][lane] = acc;
  }
  __syncthreads();

  // GEMM phase: 4x4 register tile. rows r0..r0+3, cols c0..c0+3.
  const int c0 = (tid & 15) * 4;
  const int r0 = (tid >> 4) * 4;
  float acc[4][4];
  #pragma unroll
  for (int i = 0; i < 4; ++i)
    #pragma unroll
    for (int j = 0; j < 4; ++j) acc[i][j] = 0.f;

  for (int k0 = 0; k0 < 64; k0 += 4) {
    float wr[4][4];
    #pragma unroll
    for (int kk = 0; kk < 4; ++kk) {
      float4 w4 = *(const float4*)&Wt[k0 + kk][c0];
      wr[kk][0] = w4.x; wr[kk][1] = w4.y; wr[kk][2] = w4.z; wr[kk][3] = w4.w;
    }
    #pragma unroll
    for (int i = 0; i < 4; ++i) {
      float4 a4 = *(const float4*)&At[r0 + i][k0];
      float ar[4] = {a4.x, a4.y, a4.z, a4.w};
      #pragma unroll
      for (int kk = 0; kk < 4; ++kk)
        #pragma unroll
        for (int j = 0; j < 4; ++j)
          acc[i][j] += ar[kk] * wr[kk][j];
    }
  }

  float bj[4];
  #pragma unroll
  for (int j = 0; j < 4; ++j) bj[j] = bias[c0 + j];

  if (!POOL) {
    #pragma unroll
    for (int i = 0; i < 4; ++i) {
      int row = rowBase + r0 + i;
      if (row < N_NODES) {
        float v0 = acc[i][0] + bj[0], v1 = acc[i][1] + bj[1];
        float v2 = acc[i][2] + bj[2], v3 = acc[i][3] + bj[3];
        if (RELU) {
          v0 = fmaxf(v0, 0.f); v1 = fmaxf(v1, 0.f);
          v2 = fmaxf(v2, 0.f); v3 = fmaxf(v3, 0.f);
        }
        ushort4 o;
        o.x = f2bf(v0); o.y = f2bf(v1); o.z = f2bf(v2); o.w = f2bf(v3);
        *(ushort4*)&Tout[(size_t)row * 64 + c0] = o;
      }
    }
  } else {
    const int row0 = rowBase + r0;
    int nvalid = N_NODES - row0;
    if (nvalid > 4) nvalid = 4;
    if (nvalid > 0) {
      int gArr[4];
      #pragma unroll
      for (int i = 0; i < 4; ++i)
        gArr[i] = (i < nvalid) ? load_idx(bPtr, flag, row0 + i) : 0;
      #pragma unroll
      for (int j = 0; j < 4; ++j) {
        int curg = gArr[0];
        float best = acc[0][j] + bj[j];
        for (int i = 1; i < nvalid; ++i) {
          float v = acc[i][j] + bj[j];
          if (gArr[i] != curg) {
            atomicMax(&pooled[curg * 64 + c0 + j], f2ord(best));
            curg = gArr[i]; best = v;
          } else {
            best = fmaxf(best, v);
          }
        }
        atomicMax(&pooled[curg * 64 + c0 + j], f2ord(best));
      }
    }
  }
}

// ---- fallback path (small ws): dense GEMM + atomic scatter ------------------

template<bool RELU_IN, bool ADD_BIAS, bool RELU_OUT>
__global__ __launch_bounds__(256) void gemm64(const float* A,
                                              const float* __restrict__ W,
                                              const float* __restrict__ b,
                                              float* C, int N) {
  __shared__ float Wt[64][68];
  __shared__ float At[64][68];
  const int tid = threadIdx.x;
  const int rowBase = blockIdx.x * 64;

  for (int i = tid; i < 4096; i += 256) {
    int k = i >> 6, c = i & 63;
    Wt[c][k] = W[i];
  }
  const float4* A4 = (const float4*)A;
  #pragma unroll
  for (int j = 0; j < 4; ++j) {
    int t4 = tid + j * 256;
    int g4 = rowBase * 16 + t4;
    float4 v = make_float4(0.f, 0.f, 0.f, 0.f);
    if (g4 < N * 16) v = A4[g4];
    if (RELU_IN) {
      v.x = fmaxf(v.x, 0.f); v.y = fmaxf(v.y, 0.f);
      v.z = fmaxf(v.z, 0.f); v.w = fmaxf(v.w, 0.f);
    }
    int r = t4 >> 4, k4 = t4 & 15;
    *(float4*)&At[r][k4 * 4] = v;
  }
  __syncthreads();

  const int c = tid & 63;
  const int r0 = (tid >> 6) * 16;
  float acc[16];
  #pragma unroll
  for (int i = 0; i < 16; ++i) acc[i] = 0.f;

  for (int k0 = 0; k0 < 64; k0 += 4) {
    float4 w = *(const float4*)&Wt[c][k0];
    #pragma unroll
    for (int i = 0; i < 16; ++i) {
      float4 a = *(const float4*)&At[r0 + i][k0];
      acc[i] += a.x * w.x + a.y * w.y + a.z * w.z + a.w * w.w;
    }
  }

  const float bias = ADD_BIAS ? b[c] : 0.f;
  #pragma unroll
  for (int i = 0; i < 16; ++i) {
    int row = rowBase + r0 + i;
    if (row < N) {
      float v = acc[i] + bias;
      if (RELU_OUT) v = fmaxf(v, 0.f);
      C[row * 64 + c] = v;
    }
  }
}

__global__ __launch_bounds__(256) void init_bias(float* __restrict__ agg,
                                                 const float* __restrict__ b, int n4) {
  int i = blockIdx.x * 256 + threadIdx.x;
  if (i >= n4) return;
  ((float4*)agg)[i] = ((const float4*)b)[i & 15];
}

__global__ __launch_bounds__(256) void scatter_add(const float* __restrict__ h,
                                                   const void* __restrict__ eiPtr,
                                                   const int* __restrict__ flag,
                                                   const float* __restrict__ ew,
                                                   float* __restrict__ agg) {
  int gtid = blockIdx.x * 256 + threadIdx.x;
  int e = gtid >> 6, lane = gtid & 63;
  if (e >= N_EDGES) return;
  int s = load_idx(eiPtr, flag, e);
  int d = load_idx(eiPtr, flag, (long long)N_EDGES + e);
  atomicAdd(&agg[d * 64 + lane], ew[e] * h[s * 64 + lane]);
}

__global__ __launch_bounds__(256) void seg_max(const float* __restrict__ h,
                                               const void* __restrict__ bPtr,
                                               const int* __restrict__ flag,
                                               unsigned* __restrict__ pooled) {
  int gtid = blockIdx.x * 256 + threadIdx.x;
  int n = gtid >> 6, lane = gtid & 63;
  if (n >= N_NODES) return;
  int g = load_idx(bPtr, flag, n);
  atomicMax(&pooled[g * 64 + lane], f2ord(h[n * 64 + lane]));
}

// ---- BatchNorm + linear head ------------------------------------------------

__global__ __launch_bounds__(256) void bn_head(const unsigned* __restrict__ pooled,
                                               const float* __restrict__ gamma,
                                               const float* __restrict__ beta,
                                               const float* __restrict__ linW,
                                               const float* __restrict__ linb,
                                               float* __restrict__ out) {
  __shared__ float P[NGRAPHS][64 + 1];
  __shared__ float mean_s[64], rstd_s[64];
  const int tid = threadIdx.x;

  for (int i = tid; i < NGRAPHS * 64; i += 256) {
    P[i >> 6][i & 63] = ord2f(pooled[i]);
  }
  __syncthreads();

  if (tid < 64) {
    float s = 0.f, ss = 0.f;
    for (int g = 0; g < NGRAPHS; ++g) {
      float v = P[g][tid];
      s += v; ss += v * v;
    }
    float m = s / (float)NGRAPHS;
    float var = ss / (float)NGRAPHS - m * m;
    mean_s[tid] = m;
    rstd_s[tid] = rsqrtf(var + BN_EPS);
  }
  __syncthreads();

  float acc = linb[0];
  #pragma unroll 8
  for (int c = 0; c < 64; ++c) {
    float normed = (P[tid][c] - mean_s[c]) * rstd_s[c] * gamma[c] + beta[c];
    acc += normed * linW[c];
  }
  out[tid] = acc;
}

// ---- launch -----------------------------------------------------------------

extern "C" void kernel_launch(void* const* d_in, const int* in_sizes, int n_in,
                              void* d_out, int out_size, void* d_ws, size_t ws_size,
                              hipStream_t stream) {
  const float* x     = (const float*)d_in[0];
  const void*  ei    = d_in[1];
  const float* ew    = (const float*)d_in[2];
  const void*  batch = d_in[3];
  const float* W1    = (const float*)d_in[4];
  const float* b1    = (const float*)d_in[5];
  const float* W2    = (const float*)d_in[6];
  const float* b2    = (const float*)d_in[7];
  const float* W3    = (const float*)d_in[8];
  const float* b3    = (const float*)d_in[9];
  const float* gamma = (const float*)d_in[10];
  const float* beta  = (const float*)d_in[11];
  const float* linW  = (const float*)d_in[12];
  const float* linb  = (const float*)d_in[13];

  char* ws = (char*)d_ws;
  const size_t MAT  = (size_t)N_NODES * 64 * sizeof(float);           // 25.6 MB
  const size_t TBL  = (size_t)N_NODES * 64 * sizeof(unsigned short);  // 12.8 MB
  const size_t CSR  = (size_t)N_EDGES * sizeof(int2);                 // 12.8 MB
  const size_t PTR  = ((size_t)(N_NODES + 1) * sizeof(int) + 255) & ~(size_t)255;

  size_t off = 0;
  int2*  tmp    = (int2*)(ws + off);           off += CSR;
  int2*  csrSW  = (int2*)(ws + off);           off += CSR;
  unsigned short* tableA = (unsigned short*)(ws + off); off += TBL;
  unsigned short* tableB = (unsigned short*)(ws + off); off += TBL;
  int*   rowPtr = (int*)(ws + off);            off += PTR;
  int*   bukCnt = (int*)(ws + off);            off += 1024;
  int*   bukBas = (int*)(ws + off);            off += 1024;
  int*   bukCur = (int*)(ws + off);            off += 1024;
  unsigned* pooled = (unsigned*)(ws + off);    off += (size_t)NGRAPHS * 64 * sizeof(unsigned);
  int*   flag   = (int*)(ws + off);            off += 256;
  const bool csrPath = (ws_size >= off) && (ws_size >= 2 * MAT + 65536 + 256);

  const int gemmBlocks = (N_NODES + 63) / 64;           // 1563
  const int nodeWaveBlocks = (N_NODES * 64) / 256;      // 25000

  detect_i64<<<1, 64, 0, stream>>>((const unsigned*)ei, flag);

  if (csrPath) {
    // ---- build CSR (bucketed counting sort) ----
    hipMemsetAsync(bukCnt, 0, 1024, stream);
    bucket_hist<<<BIN_BLOCKS, 256, 0, stream>>>(ei, flag, bukCnt);
    bucket_scan<<<1, 256, 0, stream>>>(bukCnt, bukBas, bukCur, rowPtr);
    binpass<<<BIN_BLOCKS, 256, 0, stream>>>(ei, flag, ew, bukCur, tmp);
    place2<<<NBUK, 256, 0, stream>>>(tmp, bukBas, rowPtr, csrSW);

    // x -> bf16 table
    to_bf16<<<(N_NODES * 16 + 255) / 256, 256, 0, stream>>>(
        (const float4*)x, (ushort4*)tableA, N_NODES * 16);

    // layer 1: pull(tableA) -> @W1+b1, relu -> tableB
    fused_layer<false, true><<<gemmBlocks, 256, 0, stream>>>(
        tableA, rowPtr, csrSW, W1, b1, tableB, nullptr, flag, nullptr);
    // layer 2: pull(tableB) -> @W2+b2, relu -> tableA
    fused_layer<false, true><<<gemmBlocks, 256, 0, stream>>>(
        tableB, rowPtr, csrSW, W2, b2, tableA, nullptr, flag, nullptr);
    // layer 3: pull(tableA) -> @W3+b3 -> segment-max pool
    hipMemsetAsync(pooled, 0, (size_t)NGRAPHS * 64 * sizeof(unsigned), stream);
    fused_layer<true, false><<<gemmBlocks, 256, 0, stream>>>(
        tableA, rowPtr, csrSW, W3, b3, nullptr, batch, flag, pooled);

    bn_head<<<1, 256, 0, stream>>>(pooled, gamma, beta, linW, linb, (float*)d_out);
  } else {
    // ---- fallback: atomic scatter path ----
    float* h   = (float*)ws;
    float* agg = (float*)(ws + MAT);
    unsigned* pooled2 = (unsigned*)(ws + 2 * MAT);
    int* flag2 = (int*)(ws + 2 * MAT + (size_t)NGRAPHS * 64 * sizeof(unsigned));
    detect_i64<<<1, 64, 0, stream>>>((const unsigned*)ei, flag2);
    const int n4 = N_NODES * 16;
    const int initBlocks = (n4 + 255) / 256;
    const int scatBlocks = (N_EDGES * 64) / 256;

    gemm64<false, false, false><<<gemmBlocks, 256, 0, stream>>>(x, W1, b1, h, N_NODES);
    init_bias<<<initBlocks, 256, 0, stream>>>(agg, b1, n4);
    scatter_add<<<scatBlocks, 256, 0, stream>>>(h, ei, flag2, ew, agg);
    gemm64<true, false, false><<<gemmBlocks, 256, 0, stream>>>(agg, W2, b2, h, N_NODES);
    init_bias<<<initBlocks, 256, 0, stream>>>(agg, b2, n4);
    scatter_add<<<scatBlocks, 256, 0, stream>>>(h, ei, flag2, ew, agg);
    gemm64<true, false, false><<<gemmBlocks, 256, 0, stream>>>(agg, W3, b3, h, N_NODES);
    init_bias<<<initBlocks, 256, 0, stream>>>(agg, b3, n4);
    scatter_add<<<scatBlocks, 256, 0, stream>>>(h, ei, flag2, ew, agg);

    hipMemsetAsync(pooled2, 0, (size_t)NGRAPHS * 64 * sizeof(unsigned), stream);
    seg_max<<<nodeWaveBlocks, 256, 0, stream>>>(agg, batch, flag2, pooled2);
    bn_head<<<1, 256, 0, stream>>>(pooled2, gamma, beta, linW, linb, (float*)d_out);
  }
}

// Round 6
// 341.095 us; speedup vs baseline: 3.6406x; 3.6406x over previous
//
#include <hip/hip_runtime.h>

#define N_NODES 100000
#define N_EDGES 1600000
#define NGRAPHS 256
#define BN_EPS 1e-5f
#define NBUK ((N_NODES + 511) >> 9)           // 196 buckets of 512 dst nodes
#define BIN_EPB 2048                          // edges per binning block
#define BIN_BLOCKS ((N_EDGES + BIN_EPB - 1) / BIN_EPB)  // 782

// ---- helpers ----------------------------------------------------------------

__device__ __forceinline__ unsigned f2ord(float f) {
  unsigned u = __float_as_uint(f);
  return (u & 0x80000000u) ? ~u : (u | 0x80000000u);
}

__device__ __forceinline__ float ord2f(unsigned u) {
  unsigned bits = (u & 0x80000000u) ? (u ^ 0x80000000u) : ~u;
  return __uint_as_float(bits);
}

__device__ __forceinline__ unsigned short f2bf(float f) {   // RNE f32 -> bf16
  unsigned u = __float_as_uint(f);
  unsigned r = u + 0x7FFFu + ((u >> 16) & 1u);
  return (unsigned short)(r >> 16);
}

__device__ __forceinline__ float bf2f(unsigned short b) {
  return __uint_as_float(((unsigned)b) << 16);
}

// Detect whether edge_index is int64 (high dwords all zero) or int32.
__global__ void detect_i64(const unsigned* __restrict__ ei, int* __restrict__ flag) {
  if (blockIdx.x == 0 && threadIdx.x == 0) {
    int f = 1;
    for (int i = 1; i < 64; i += 2) {
      if (ei[i] != 0u) { f = 0; break; }
    }
    *flag = f;
  }
}

__device__ __forceinline__ int load_idx(const void* p, const int* flag, long long i) {
  return (*flag) ? (int)((const long long*)p)[i] : ((const int*)p)[i];
}

// ---- f32 -> bf16 table conversion -------------------------------------------

__global__ __launch_bounds__(256) void to_bf16(const float4* __restrict__ in,
                                               ushort4* __restrict__ out, int n4) {
  int i = blockIdx.x * 256 + threadIdx.x;
  if (i >= n4) return;
  float4 v = in[i];
  ushort4 o;
  o.x = f2bf(v.x); o.y = f2bf(v.y); o.z = f2bf(v.z); o.w = f2bf(v.w);
  out[i] = o;
}

// ---- CSR build (bucketed counting sort) -------------------------------------

__global__ __launch_bounds__(256) void bucket_hist(const void* __restrict__ eiPtr,
                                                   const int* __restrict__ flag,
                                                   int* __restrict__ bucketCount) {
  __shared__ int cnt[NBUK];
  const int tid = threadIdx.x;
  for (int i = tid; i < NBUK; i += 256) cnt[i] = 0;
  __syncthreads();
  const long long chunk0 = (long long)blockIdx.x * BIN_EPB;
  const bool i64 = (*flag != 0);
  #pragma unroll
  for (int j = 0; j < 8; ++j) {
    long long e = chunk0 + j * 256 + tid;
    if (e < N_EDGES) {
      int d = i64 ? (int)((const long long*)eiPtr)[N_EDGES + e]
                  : ((const int*)eiPtr)[N_EDGES + e];
      atomicAdd(&cnt[d >> 9], 1);
    }
  }
  __syncthreads();
  for (int b = tid; b < NBUK; b += 256) {
    int c = cnt[b];
    if (c) atomicAdd(&bucketCount[b], c);
  }
}

__global__ void bucket_scan(const int* __restrict__ bucketCount,
                            int* __restrict__ bucketBase,
                            int* __restrict__ bucketCursor,
                            int* __restrict__ rowPtr) {
  __shared__ int lds[256];
  const int tid = threadIdx.x;
  lds[tid] = (tid < NBUK) ? bucketCount[tid] : 0;
  __syncthreads();
  int own = lds[tid];
  for (int off = 1; off < 256; off <<= 1) {
    int t = (tid >= off) ? lds[tid - off] : 0;
    __syncthreads();
    lds[tid] += t;
    __syncthreads();
  }
  int excl = lds[tid] - own;
  if (tid < NBUK) { bucketBase[tid] = excl; bucketCursor[tid] = excl; }
  if (tid == 0) { bucketBase[NBUK] = N_EDGES; rowPtr[N_NODES] = N_EDGES; }
}

// Bin edges by dst>>9 into bucket-grouped tmp. Packed: x = src | (localdst<<18).
__global__ __launch_bounds__(256) void binpass(const void* __restrict__ eiPtr,
                                               const int* __restrict__ flag,
                                               const float* __restrict__ ew,
                                               int* __restrict__ bucketCursor,
                                               int2* __restrict__ tmp) {
  __shared__ int cnt[NBUK];
  __shared__ int base[NBUK];
  const int tid = threadIdx.x;
  const long long chunk0 = (long long)blockIdx.x * BIN_EPB;
  for (int i = tid; i < NBUK; i += 256) cnt[i] = 0;
  __syncthreads();
  int pk[8], wb[8], rk[8], bk[8];
  const bool i64 = (*flag != 0);
  #pragma unroll
  for (int j = 0; j < 8; ++j) {
    long long e = chunk0 + j * 256 + tid;
    rk[j] = -1;
    if (e < N_EDGES) {
      int s, d;
      if (i64) {
        const long long* ei = (const long long*)eiPtr;
        s = (int)ei[e]; d = (int)ei[N_EDGES + e];
      } else {
        const int* ei = (const int*)eiPtr;
        s = ei[e]; d = ei[N_EDGES + e];
      }
      wb[j] = __float_as_int(ew[e]);
      bk[j] = d >> 9;
      pk[j] = s | ((d & 511) << 18);
      rk[j] = atomicAdd(&cnt[bk[j]], 1);
    }
  }
  __syncthreads();
  for (int b = tid; b < NBUK; b += 256) {
    int c = cnt[b];
    base[b] = c ? atomicAdd(&bucketCursor[b], c) : 0;
  }
  __syncthreads();
  #pragma unroll
  for (int j = 0; j < 8; ++j) {
    if (rk[j] >= 0) {
      int2 r; r.x = pk[j]; r.y = wb[j];
      tmp[base[bk[j]] + rk[j]] = r;
    }
  }
}

// One block per bucket: local hist(512) + LDS scan -> rowPtr slice, then
// scatter within the bucket's L2-hot CSR window.
__global__ __launch_bounds__(256) void place2(const int2* __restrict__ tmp,
                                              const int* __restrict__ bucketBase,
                                              int* __restrict__ rowPtr,
                                              int2* __restrict__ csrSW) {
  __shared__ int cnt[512];
  __shared__ int sc[256];
  __shared__ int cur[512];
  const int b = blockIdx.x;
  const int tid = threadIdx.x;
  const int beg = bucketBase[b];
  const int end = bucketBase[b + 1];
  cnt[tid] = 0; cnt[tid + 256] = 0;
  __syncthreads();
  for (int i = beg + tid; i < end; i += 256) {
    atomicAdd(&cnt[(tmp[i].x >> 18) & 511], 1);
  }
  __syncthreads();
  int c0 = cnt[2 * tid], c1 = cnt[2 * tid + 1];
  int pairSum = c0 + c1;
  sc[tid] = pairSum;
  __syncthreads();
  for (int off = 1; off < 256; off <<= 1) {
    int t = (tid >= off) ? sc[tid - off] : 0;
    __syncthreads();
    sc[tid] += t;
    __syncthreads();
  }
  int exclPair = sc[tid] - pairSum;
  int base0 = beg + exclPair;
  int base1 = base0 + c0;
  int g0 = (b << 9) + 2 * tid;
  if (g0 < N_NODES)     rowPtr[g0]     = base0;
  if (g0 + 1 < N_NODES) rowPtr[g0 + 1] = base1;
  cur[2 * tid] = base0;
  cur[2 * tid + 1] = base1;
  __syncthreads();
  for (int i = beg + tid; i < end; i += 256) {
    int2 e = tmp[i];
    int pos = atomicAdd(&cur[(e.x >> 18) & 511], 1);
    int2 r; r.x = e.x & 0x3FFFF; r.y = e.y;
    csrSW[pos] = r;
  }
}

// ---- pull aggregation (bf16 table): coalesced meta + shfl, 8-deep gathers ---

__global__ __launch_bounds__(256) void pull_agg(const unsigned short* __restrict__ T,
                                                const int* __restrict__ rowPtr,
                                                const int2* __restrict__ csrSW,
                                                float* __restrict__ out) {
  int gtid = blockIdx.x * 256 + threadIdx.x;
  int n = gtid >> 6, lane = gtid & 63;
  if (n >= N_NODES) return;
  const int beg = rowPtr[n], end = rowPtr[n + 1];
  float acc = 0.f;
  for (int base = beg; base < end; base += 64) {
    const int m = min(64, end - base);
    int idx = base + (lane < m ? lane : m - 1);
    int2 meta = csrSW[idx];
    int src = meta.x;
    float w = __int_as_float(meta.y);
    int i = 0;
    for (; i + 8 <= m; i += 8) {
      float v[8], wv[8];
      #pragma unroll
      for (int j = 0; j < 8; ++j) {
        int s = __shfl(src, i + j);
        wv[j] = __shfl(w, i + j);
        v[j] = bf2f(T[(size_t)s * 64 + lane]);
      }
      #pragma unroll
      for (int j = 0; j < 8; ++j) acc += wv[j] * v[j];
    }
    for (; i < m; ++i) {
      int s = __shfl(src, i);
      float wv = __shfl(w, i);
      acc += wv * bf2f(T[(size_t)s * 64 + lane]);
    }
  }
  out[(size_t)n * 64 + lane] = acc;
}

// ---- GEMM: bf16Out[N][64] = relu(A[N][64] @ W + b) --------------------------

template<bool RELU_OUT>
__global__ __launch_bounds__(256) void gemm64_bf16(const float* __restrict__ A,
                                                   const float* __restrict__ W,
                                                   const float* __restrict__ b,
                                                   unsigned short* __restrict__ Tout,
                                                   int N) {
  __shared__ float Wt[64][68];
  __shared__ float At[64][68];
  const int tid = threadIdx.x;
  const int rowBase = blockIdx.x * 64;

  for (int i = tid; i < 4096; i += 256) {
    int k = i >> 6, c = i & 63;
    Wt[c][k] = W[i];
  }
  const float4* A4 = (const float4*)A;
  #pragma unroll
  for (int j = 0; j < 4; ++j) {
    int t4 = tid + j * 256;
    int g4 = rowBase * 16 + t4;
    float4 v = make_float4(0.f, 0.f, 0.f, 0.f);
    if (g4 < N * 16) v = A4[g4];
    int r = t4 >> 4, k4 = t4 & 15;
    *(float4*)&At[r][k4 * 4] = v;
  }
  __syncthreads();

  const int c = tid & 63;
  const int r0 = (tid >> 6) * 16;
  float acc[16];
  #pragma unroll
  for (int i = 0; i < 16; ++i) acc[i] = 0.f;

  for (int k0 = 0; k0 < 64; k0 += 4) {
    float4 w = *(const float4*)&Wt[c][k0];
    #pragma unroll
    for (int i = 0; i < 16; ++i) {
      float4 a = *(const float4*)&At[r0 + i][k0];
      acc[i] += a.x * w.x + a.y * w.y + a.z * w.z + a.w * w.w;
    }
  }

  const float bias = b[c];
  #pragma unroll
  for (int i = 0; i < 16; ++i) {
    int row = rowBase + r0 + i;
    if (row < N) {
      float v = acc[i] + bias;
      if (RELU_OUT) v = fmaxf(v, 0.f);
      Tout[(size_t)row * 64 + c] = f2bf(v);
    }
  }
}

// ---- layer-3 GEMM with fused segment-max pooling epilogue -------------------

__global__ __launch_bounds__(256) void gemm64_pool(const float* __restrict__ A,
                                                   const float* __restrict__ W,
                                                   const float* __restrict__ b,
                                                   const void* __restrict__ bPtr,
                                                   const int* __restrict__ flag,
                                                   unsigned* __restrict__ pooled,
                                                   int N) {
  __shared__ float Wt[64][68];
  __shared__ float At[64][68];
  const int tid = threadIdx.x;
  const int rowBase = blockIdx.x * 64;

  for (int i = tid; i < 4096; i += 256) {
    int k = i >> 6, c = i & 63;
    Wt[c][k] = W[i];
  }
  const float4* A4 = (const float4*)A;
  #pragma unroll
  for (int j = 0; j < 4; ++j) {
    int t4 = tid + j * 256;
    int g4 = rowBase * 16 + t4;
    float4 v = make_float4(0.f, 0.f, 0.f, 0.f);
    if (g4 < N * 16) v = A4[g4];
    int r = t4 >> 4, k4 = t4 & 15;
    *(float4*)&At[r][k4 * 4] = v;
  }
  __syncthreads();

  const int c = tid & 63;
  const int r0 = (tid >> 6) * 16;
  float acc[16];
  #pragma unroll
  for (int i = 0; i < 16; ++i) acc[i] = 0.f;

  for (int k0 = 0; k0 < 64; k0 += 4) {
    float4 w = *(const float4*)&Wt[c][k0];
    #pragma unroll
    for (int i = 0; i < 16; ++i) {
      float4 a = *(const float4*)&At[r0 + i][k0];
      acc[i] += a.x * w.x + a.y * w.y + a.z * w.z + a.w * w.w;
    }
  }

  // epilogue: run-length max over sorted batch, then atomicMax per run
  const float bias = b[c];
  const int row0 = rowBase + r0;
  if (row0 < N) {
    int curg = load_idx(bPtr, flag, row0);
    float best = acc[0] + bias;
    #pragma unroll
    for (int i = 1; i < 16; ++i) {
      int row = row0 + i;
      if (row >= N) break;
      int g = load_idx(bPtr, flag, row);
      float v = acc[i] + bias;
      if (g != curg) {
        atomicMax(&pooled[curg * 64 + c], f2ord(best));
        curg = g; best = v;
      } else {
        best = fmaxf(best, v);
      }
    }
    atomicMax(&pooled[curg * 64 + c], f2ord(best));
  }
}

// ---- fallback path (small ws): dense GEMM + atomic scatter ------------------

template<bool RELU_IN, bool ADD_BIAS, bool RELU_OUT>
__global__ __launch_bounds__(256) void gemm64(const float* A,
                                              const float* __restrict__ W,
                                              const float* __restrict__ b,
                                              float* C, int N) {
  __shared__ float Wt[64][68];
  __shared__ float At[64][68];
  const int tid = threadIdx.x;
  const int rowBase = blockIdx.x * 64;

  for (int i = tid; i < 4096; i += 256) {
    int k = i >> 6, c = i & 63;
    Wt[c][k] = W[i];
  }
  const float4* A4 = (const float4*)A;
  #pragma unroll
  for (int j = 0; j < 4; ++j) {
    int t4 = tid + j * 256;
    int g4 = rowBase * 16 + t4;
    float4 v = make_float4(0.f, 0.f, 0.f, 0.f);
    if (g4 < N * 16) v = A4[g4];
    if (RELU_IN) {
      v.x = fmaxf(v.x, 0.f); v.y = fmaxf(v.y, 0.f);
      v.z = fmaxf(v.z, 0.f); v.w = fmaxf(v.w, 0.f);
    }
    int r = t4 >> 4, k4 = t4 & 15;
    *(float4*)&At[r][k4 * 4] = v;
  }
  __syncthreads();

  const int c = tid & 63;
  const int r0 = (tid >> 6) * 16;
  float acc[16];
  #pragma unroll
  for (int i = 0; i < 16; ++i) acc[i] = 0.f;

  for (int k0 = 0; k0 < 64; k0 += 4) {
    float4 w = *(const float4*)&Wt[c][k0];
    #pragma unroll
    for (int i = 0; i < 16; ++i) {
      float4 a = *(const float4*)&At[r0 + i][k0];
      acc[i] += a.x * w.x + a.y * w.y + a.z * w.z + a.w * w.w;
    }
  }

  const float bias = ADD_BIAS ? b[c] : 0.f;
  #pragma unroll
  for (int i = 0; i < 16; ++i) {
    int row = rowBase + r0 + i;
    if (row < N) {
      float v = acc[i] + bias;
      if (RELU_OUT) v = fmaxf(v, 0.f);
      C[row * 64 + c] = v;
    }
  }
}

__global__ __launch_bounds__(256) void init_bias(float* __restrict__ agg,
                                                 const float* __restrict__ b, int n4) {
  int i = blockIdx.x * 256 + threadIdx.x;
  if (i >= n4) return;
  ((float4*)agg)[i] = ((const float4*)b)[i & 15];
}

__global__ __launch_bounds__(256) void scatter_add(const float* __restrict__ h,
                                                   const void* __restrict__ eiPtr,
                                                   const int* __restrict__ flag,
                                                   const float* __restrict__ ew,
                                                   float* __restrict__ agg) {
  int gtid = blockIdx.x * 256 + threadIdx.x;
  int e = gtid >> 6, lane = gtid & 63;
  if (e >= N_EDGES) return;
  int s = load_idx(eiPtr, flag, e);
  int d = load_idx(eiPtr, flag, (long long)N_EDGES + e);
  atomicAdd(&agg[d * 64 + lane], ew[e] * h[s * 64 + lane]);
}

__global__ __launch_bounds__(256) void seg_max(const float* __restrict__ h,
                                               const void* __restrict__ bPtr,
                                               const int* __restrict__ flag,
                                               unsigned* __restrict__ pooled) {
  int gtid = blockIdx.x * 256 + threadIdx.x;
  int n = gtid >> 6, lane = gtid & 63;
  if (n >= N_NODES) return;
  int g = load_idx(bPtr, flag, n);
  atomicMax(&pooled[g * 64 + lane], f2ord(h[n * 64 + lane]));
}

// ---- BatchNorm + linear head ------------------------------------------------

__global__ __launch_bounds__(256) void bn_head(const unsigned* __restrict__ pooled,
                                               const float* __restrict__ gamma,
                                               const float* __restrict__ beta,
                                               const float* __restrict__ linW,
                                               const float* __restrict__ linb,
                                               float* __restrict__ out) {
  __shared__ float P[NGRAPHS][64 + 1];
  __shared__ float mean_s[64], rstd_s[64];
  const int tid = threadIdx.x;

  for (int i = tid; i < NGRAPHS * 64; i += 256) {
    P[i >> 6][i & 63] = ord2f(pooled[i]);
  }
  __syncthreads();

  if (tid < 64) {
    float s = 0.f, ss = 0.f;
    for (int g = 0; g < NGRAPHS; ++g) {
      float v = P[g][tid];
      s += v; ss += v * v;
    }
    float m = s / (float)NGRAPHS;
    float var = ss / (float)NGRAPHS - m * m;
    mean_s[tid] = m;
    rstd_s[tid] = rsqrtf(var + BN_EPS);
  }
  __syncthreads();

  float acc = linb[0];
  #pragma unroll 8
  for (int c = 0; c < 64; ++c) {
    float normed = (P[tid][c] - mean_s[c]) * rstd_s[c] * gamma[c] + beta[c];
    acc += normed * linW[c];
  }
  out[tid] = acc;
}

// ---- launch -----------------------------------------------------------------

extern "C" void kernel_launch(void* const* d_in, const int* in_sizes, int n_in,
                              void* d_out, int out_size, void* d_ws, size_t ws_size,
                              hipStream_t stream) {
  const float* x     = (const float*)d_in[0];
  const void*  ei    = d_in[1];
  const float* ew    = (const float*)d_in[2];
  const void*  batch = d_in[3];
  const float* W1    = (const float*)d_in[4];
  const float* b1    = (const float*)d_in[5];
  const float* W2    = (const float*)d_in[6];
  const float* b2    = (const float*)d_in[7];
  const float* W3    = (const float*)d_in[8];
  const float* b3    = (const float*)d_in[9];
  const float* gamma = (const float*)d_in[10];
  const float* beta  = (const float*)d_in[11];
  const float* linW  = (const float*)d_in[12];
  const float* linb  = (const float*)d_in[13];

  char* ws = (char*)d_ws;
  const size_t MAT  = (size_t)N_NODES * 64 * sizeof(float);           // 25.6 MB
  const size_t TBL  = (size_t)N_NODES * 64 * sizeof(unsigned short);  // 12.8 MB
  const size_t CSR  = (size_t)N_EDGES * sizeof(int2);                 // 12.8 MB
  const size_t PTR  = ((size_t)(N_NODES + 1) * sizeof(int) + 255) & ~(size_t)255;

  size_t off = 0;
  float* aggF32 = (float*)(ws + off);          off += MAT;  // alias: tmp (CSR build)
  int2*  csrSW  = (int2*)(ws + off);           off += CSR;
  unsigned short* tableA = (unsigned short*)(ws + off); off += TBL;
  unsigned short* tableB = (unsigned short*)(ws + off); off += TBL;
  int*   rowPtr = (int*)(ws + off);            off += PTR;
  int*   bukCnt = (int*)(ws + off);            off += 1024;
  int*   bukBas = (int*)(ws + off);            off += 1024;
  int*   bukCur = (int*)(ws + off);            off += 1024;
  unsigned* pooled = (unsigned*)(ws + off);    off += (size_t)NGRAPHS * 64 * sizeof(unsigned);
  int*   flag   = (int*)(ws + off);            off += 256;
  const bool csrPath = (ws_size >= off);

  const int gemmBlocks = (N_NODES + 63) / 64;           // 1563
  const int nodeWaveBlocks = (N_NODES * 64) / 256;      // 25000

  detect_i64<<<1, 64, 0, stream>>>((const unsigned*)ei, flag);

  if (csrPath) {
    int2* tmp = (int2*)aggF32;   // 12.8 MB, only live during CSR build
    // ---- build CSR (bucketed counting sort) ----
    hipMemsetAsync(bukCnt, 0, 1024, stream);
    bucket_hist<<<BIN_BLOCKS, 256, 0, stream>>>(ei, flag, bukCnt);
    bucket_scan<<<1, 256, 0, stream>>>(bukCnt, bukBas, bukCur, rowPtr);
    binpass<<<BIN_BLOCKS, 256, 0, stream>>>(ei, flag, ew, bukCur, tmp);
    place2<<<NBUK, 256, 0, stream>>>(tmp, bukBas, rowPtr, csrSW);

    // x -> bf16 table
    to_bf16<<<(N_NODES * 16 + 255) / 256, 256, 0, stream>>>(
        (const float4*)x, (ushort4*)tableA, N_NODES * 16);

    // layer 1
    pull_agg<<<nodeWaveBlocks, 256, 0, stream>>>(tableA, rowPtr, csrSW, aggF32);
    gemm64_bf16<true><<<gemmBlocks, 256, 0, stream>>>(aggF32, W1, b1, tableB, N_NODES);
    // layer 2
    pull_agg<<<nodeWaveBlocks, 256, 0, stream>>>(tableB, rowPtr, csrSW, aggF32);
    gemm64_bf16<true><<<gemmBlocks, 256, 0, stream>>>(aggF32, W2, b2, tableA, N_NODES);
    // layer 3: pull, then GEMM with fused bias + segment-max pooling
    pull_agg<<<nodeWaveBlocks, 256, 0, stream>>>(tableA, rowPtr, csrSW, aggF32);
    hipMemsetAsync(pooled, 0, (size_t)NGRAPHS * 64 * sizeof(unsigned), stream);
    gemm64_pool<<<gemmBlocks, 256, 0, stream>>>(aggF32, W3, b3, batch, flag, pooled, N_NODES);

    bn_head<<<1, 256, 0, stream>>>(pooled, gamma, beta, linW, linb, (float*)d_out);
  } else {
    // ---- fallback: atomic scatter path ----
    float* h   = (float*)ws;
    float* agg = (float*)(ws + MAT);
    unsigned* pooled2 = (unsigned*)(ws + 2 * MAT);
    int* flag2 = (int*)(ws + 2 * MAT + (size_t)NGRAPHS * 64 * sizeof(unsigned));
    detect_i64<<<1, 64, 0, stream>>>((const unsigned*)ei, flag2);
    const int n4 = N_NODES * 16;
    const int initBlocks = (n4 + 255) / 256;
    const int scatBlocks = (N_EDGES * 64) / 256;

    gemm64<false, false, false><<<gemmBlocks, 256, 0, stream>>>(x, W1, b1, h, N_NODES);
    init_bias<<<initBlocks, 256, 0, stream>>>(agg, b1, n4);
    scatter_add<<<scatBlocks, 256, 0, stream>>>(h, ei, flag2, ew, agg);
    gemm64<true, false, false><<<gemmBlocks, 256, 0, stream>>>(agg, W2, b2, h, N_NODES);
    init_bias<<<initBlocks, 256, 0, stream>>>(agg, b2, n4);
    scatter_add<<<scatBlocks, 256, 0, stream>>>(h, ei, flag2, ew, agg);
    gemm64<true, false, false><<<gemmBlocks, 256, 0, stream>>>(agg, W3, b3, h, N_NODES);
    init_bias<<<initBlocks, 256, 0, stream>>>(agg, b3, n4);
    scatter_add<<<scatBlocks, 256, 0, stream>>>(h, ei, flag2, ew, agg);

    hipMemsetAsync(pooled2, 0, (size_t)NGRAPHS * 64 * sizeof(unsigned), stream);
    seg_max<<<nodeWaveBlocks, 256, 0, stream>>>(agg, batch, flag2, pooled2);
    bn_head<<<1, 256, 0, stream>>>(pooled2, gamma, beta, linW, linb, (float*)d_out);
  }
}

// Round 7
// 297.180 us; speedup vs baseline: 4.1786x; 1.1478x over previous
//
#include <hip/hip_runtime.h>

#define N_NODES 100000
#define N_EDGES 1600000
#define NGRAPHS 256
#define BN_EPS 1e-5f
#define NBUK ((N_NODES + 511) >> 9)           // 196 buckets of 512 dst nodes
#define BIN_EPB 2048                          // edges per binning block
#define BIN_BLOCKS ((N_EDGES + BIN_EPB - 1) / BIN_EPB)  // 782
#define POOL_RUN 8

// ---- helpers ----------------------------------------------------------------

__device__ __forceinline__ unsigned f2ord(float f) {
  unsigned u = __float_as_uint(f);
  return (u & 0x80000000u) ? ~u : (u | 0x80000000u);
}

__device__ __forceinline__ float ord2f(unsigned u) {
  unsigned bits = (u & 0x80000000u) ? (u ^ 0x80000000u) : ~u;
  return __uint_as_float(bits);
}

__device__ __forceinline__ unsigned short f2bf(float f) {   // RNE f32 -> bf16
  unsigned u = __float_as_uint(f);
  unsigned r = u + 0x7FFFu + ((u >> 16) & 1u);
  return (unsigned short)(r >> 16);
}

__device__ __forceinline__ float bf2f(unsigned short b) {
  return __uint_as_float(((unsigned)b) << 16);
}

// Detect whether edge_index is int64 (high dwords all zero) or int32.
__global__ void detect_i64(const unsigned* __restrict__ ei, int* __restrict__ flag) {
  if (blockIdx.x == 0 && threadIdx.x == 0) {
    int f = 1;
    for (int i = 1; i < 64; i += 2) {
      if (ei[i] != 0u) { f = 0; break; }
    }
    *flag = f;
  }
}

__device__ __forceinline__ int load_idx(const void* p, const int* flag, long long i) {
  return (*flag) ? (int)((const long long*)p)[i] : ((const int*)p)[i];
}

// ---- CSR build (bucketed counting sort) -------------------------------------

__global__ __launch_bounds__(256) void bucket_hist(const void* __restrict__ eiPtr,
                                                   const int* __restrict__ flag,
                                                   int* __restrict__ bucketCount) {
  __shared__ int cnt[NBUK];
  const int tid = threadIdx.x;
  for (int i = tid; i < NBUK; i += 256) cnt[i] = 0;
  __syncthreads();
  const long long chunk0 = (long long)blockIdx.x * BIN_EPB;
  const bool i64 = (*flag != 0);
  #pragma unroll
  for (int j = 0; j < 8; ++j) {
    long long e = chunk0 + j * 256 + tid;
    if (e < N_EDGES) {
      int d = i64 ? (int)((const long long*)eiPtr)[N_EDGES + e]
                  : ((const int*)eiPtr)[N_EDGES + e];
      atomicAdd(&cnt[d >> 9], 1);
    }
  }
  __syncthreads();
  for (int b = tid; b < NBUK; b += 256) {
    int c = cnt[b];
    if (c) atomicAdd(&bucketCount[b], c);
  }
}

__global__ void bucket_scan(const int* __restrict__ bucketCount,
                            int* __restrict__ bucketBase,
                            int* __restrict__ bucketCursor,
                            int* __restrict__ rowPtr) {
  __shared__ int lds[256];
  const int tid = threadIdx.x;
  lds[tid] = (tid < NBUK) ? bucketCount[tid] : 0;
  __syncthreads();
  int own = lds[tid];
  for (int off = 1; off < 256; off <<= 1) {
    int t = (tid >= off) ? lds[tid - off] : 0;
    __syncthreads();
    lds[tid] += t;
    __syncthreads();
  }
  int excl = lds[tid] - own;
  if (tid < NBUK) { bucketBase[tid] = excl; bucketCursor[tid] = excl; }
  if (tid == 0) { bucketBase[NBUK] = N_EDGES; rowPtr[N_NODES] = N_EDGES; }
}

// Bin edges by dst>>9 into bucket-grouped tmp. Packed: x = src | (localdst<<18).
__global__ __launch_bounds__(256) void binpass(const void* __restrict__ eiPtr,
                                               const int* __restrict__ flag,
                                               const float* __restrict__ ew,
                                               int* __restrict__ bucketCursor,
                                               int2* __restrict__ tmp) {
  __shared__ int cnt[NBUK];
  __shared__ int base[NBUK];
  const int tid = threadIdx.x;
  const long long chunk0 = (long long)blockIdx.x * BIN_EPB;
  for (int i = tid; i < NBUK; i += 256) cnt[i] = 0;
  __syncthreads();
  int pk[8], wb[8], rk[8], bk[8];
  const bool i64 = (*flag != 0);
  #pragma unroll
  for (int j = 0; j < 8; ++j) {
    long long e = chunk0 + j * 256 + tid;
    rk[j] = -1;
    if (e < N_EDGES) {
      int s, d;
      if (i64) {
        const long long* ei = (const long long*)eiPtr;
        s = (int)ei[e]; d = (int)ei[N_EDGES + e];
      } else {
        const int* ei = (const int*)eiPtr;
        s = ei[e]; d = ei[N_EDGES + e];
      }
      wb[j] = __float_as_int(ew[e]);
      bk[j] = d >> 9;
      pk[j] = s | ((d & 511) << 18);
      rk[j] = atomicAdd(&cnt[bk[j]], 1);
    }
  }
  __syncthreads();
  for (int b = tid; b < NBUK; b += 256) {
    int c = cnt[b];
    base[b] = c ? atomicAdd(&bucketCursor[b], c) : 0;
  }
  __syncthreads();
  #pragma unroll
  for (int j = 0; j < 8; ++j) {
    if (rk[j] >= 0) {
      int2 r; r.x = pk[j]; r.y = wb[j];
      tmp[base[bk[j]] + rk[j]] = r;
    }
  }
}

// One block per bucket: local hist(512) + LDS scan -> rowPtr slice, then
// scatter within the bucket's L2-hot CSR window.
__global__ __launch_bounds__(256) void place2(const int2* __restrict__ tmp,
                                              const int* __restrict__ bucketBase,
                                              int* __restrict__ rowPtr,
                                              int2* __restrict__ csrSW) {
  __shared__ int cnt[512];
  __shared__ int sc[256];
  __shared__ int cur[512];
  const int b = blockIdx.x;
  const int tid = threadIdx.x;
  const int beg = bucketBase[b];
  const int end = bucketBase[b + 1];
  cnt[tid] = 0; cnt[tid + 256] = 0;
  __syncthreads();
  for (int i = beg + tid; i < end; i += 256) {
    atomicAdd(&cnt[(tmp[i].x >> 18) & 511], 1);
  }
  __syncthreads();
  int c0 = cnt[2 * tid], c1 = cnt[2 * tid + 1];
  int pairSum = c0 + c1;
  sc[tid] = pairSum;
  __syncthreads();
  for (int off = 1; off < 256; off <<= 1) {
    int t = (tid >= off) ? sc[tid - off] : 0;
    __syncthreads();
    sc[tid] += t;
    __syncthreads();
  }
  int exclPair = sc[tid] - pairSum;
  int base0 = beg + exclPair;
  int base1 = base0 + c0;
  int g0 = (b << 9) + 2 * tid;
  if (g0 < N_NODES)     rowPtr[g0]     = base0;
  if (g0 + 1 < N_NODES) rowPtr[g0 + 1] = base1;
  cur[2 * tid] = base0;
  cur[2 * tid + 1] = base1;
  __syncthreads();
  for (int i = beg + tid; i < end; i += 256) {
    int2 e = tmp[i];
    int pos = atomicAdd(&cur[(e.x >> 18) & 511], 1);
    int2 r; r.x = e.x & 0x3FFFF; r.y = e.y;
    csrSW[pos] = r;
  }
}

// ---- GEMM: u[N][64](bf16) = A[N][64] @ W  (no bias / no relu) ---------------
// F32IN: A is fp32 (layer 1, reads x). else A is bf16 table.

template<bool F32IN>
__global__ __launch_bounds__(256) void gemm_u(const void* __restrict__ Ain,
                                              const float* __restrict__ W,
                                              unsigned short* __restrict__ Uout,
                                              int N) {
  __shared__ float Wt[64][68];   // Wt[c][k]
  __shared__ float At[64][68];
  const int tid = threadIdx.x;
  const int rowBase = blockIdx.x * 64;

  for (int i = tid; i < 4096; i += 256) {
    int k = i >> 6, c = i & 63;
    Wt[c][k] = W[i];
  }
  if (F32IN) {
    const float4* A4 = (const float4*)Ain;
    #pragma unroll
    for (int j = 0; j < 4; ++j) {
      int t4 = tid + j * 256;
      int g4 = rowBase * 16 + t4;
      float4 v = make_float4(0.f, 0.f, 0.f, 0.f);
      if (g4 < N * 16) v = A4[g4];
      int r = t4 >> 4, k4 = t4 & 15;
      *(float4*)&At[r][k4 * 4] = v;
    }
  } else {
    const uint4* A16 = (const uint4*)Ain;   // 8 bf16 per uint4; 8 uint4 per row
    #pragma unroll
    for (int j = 0; j < 2; ++j) {
      int q = tid + j * 256;                // 0..511
      int r = q >> 3, c8 = (q & 7) * 8;
      int grow = rowBase + r;
      uint4 v = make_uint4(0u, 0u, 0u, 0u);
      if (grow < N) v = A16[(size_t)grow * 8 + (q & 7)];
      float4 f0, f1;
      f0.x = bf2f((unsigned short)(v.x & 0xFFFFu)); f0.y = bf2f((unsigned short)(v.x >> 16));
      f0.z = bf2f((unsigned short)(v.y & 0xFFFFu)); f0.w = bf2f((unsigned short)(v.y >> 16));
      f1.x = bf2f((unsigned short)(v.z & 0xFFFFu)); f1.y = bf2f((unsigned short)(v.z >> 16));
      f1.z = bf2f((unsigned short)(v.w & 0xFFFFu)); f1.w = bf2f((unsigned short)(v.w >> 16));
      *(float4*)&At[r][c8] = f0;
      *(float4*)&At[r][c8 + 4] = f1;
    }
  }
  __syncthreads();

  const int c = tid & 63;
  const int r0 = (tid >> 6) * 16;
  float acc[16];
  #pragma unroll
  for (int i = 0; i < 16; ++i) acc[i] = 0.f;

  for (int k0 = 0; k0 < 64; k0 += 4) {
    float4 w = *(const float4*)&Wt[c][k0];
    #pragma unroll
    for (int i = 0; i < 16; ++i) {
      float4 a = *(const float4*)&At[r0 + i][k0];
      acc[i] += a.x * w.x + a.y * w.y + a.z * w.z + a.w * w.w;
    }
  }

  #pragma unroll
  for (int i = 0; i < 16; ++i) {
    int row = rowBase + r0 + i;
    if (row < N) Uout[(size_t)row * 64 + c] = f2bf(acc[i]);
  }
}

// ---- pull gather core: node total into float2 (both halves hold result) -----
// Lane layout: l = lane&31 covers features 2l,2l+1 (ushort2); h = lane>>5
// processes edges k+h of each pair. Cross-half shfl_xor reduce at the end.

__device__ __forceinline__ float2 gather_node(const unsigned short* __restrict__ Trow,
                                              const int2* __restrict__ csrSW,
                                              int beg, int end, int lane, int h) {
  float accx = 0.f, accy = 0.f;
  for (int base = beg; base < end; base += 64) {
    const int m = min(64, end - base);
    int idx = base + (lane < m ? lane : m - 1);
    int2 meta = csrSW[idx];
    int src = meta.x;
    float w = __int_as_float(meta.y);
    int k = 0;
    for (; k + 16 <= m; k += 16) {          // full blocks: no clamping
      unsigned v[8]; float wv[8];
      #pragma unroll
      for (int j = 0; j < 8; ++j) {
        int e = k + 2 * j + h;
        int s = __shfl(src, e);
        wv[j] = __shfl(w, e);
        v[j] = *(const unsigned*)(Trow + (size_t)s * 64);
      }
      #pragma unroll
      for (int j = 0; j < 8; ++j) {
        accx += wv[j] * __uint_as_float(v[j] << 16);
        accy += wv[j] * __uint_as_float(v[j] & 0xFFFF0000u);
      }
    }
    if (k < m) {                            // clamped tail (wave-uniform branch)
      unsigned v[8]; float wv[8];
      #pragma unroll
      for (int j = 0; j < 8; ++j) {
        int e = k + 2 * j + h;
        int ec = e < m - 1 ? e : m - 1;
        int s = __shfl(src, ec);
        float wj = __shfl(w, ec);
        wv[j] = (e < m) ? wj : 0.f;
        v[j] = *(const unsigned*)(Trow + (size_t)s * 64);
      }
      #pragma unroll
      for (int j = 0; j < 8; ++j) {
        accx += wv[j] * __uint_as_float(v[j] << 16);
        accy += wv[j] * __uint_as_float(v[j] & 0xFFFF0000u);
      }
    }
  }
  accx += __shfl_xor(accx, 32);
  accy += __shfl_xor(accy, 32);
  return make_float2(accx, accy);
}

// ---- pull + bias + relu -> bf16 table ---------------------------------------

__global__ __launch_bounds__(256) void pull_relu(const unsigned short* __restrict__ T,
                                                 const int* __restrict__ rowPtr,
                                                 const int2* __restrict__ csrSW,
                                                 const float* __restrict__ bias,
                                                 unsigned short* __restrict__ Hout) {
  int wid = (blockIdx.x * 256 + threadIdx.x) >> 6;
  int lane = threadIdx.x & 63;
  if (wid >= N_NODES) return;
  const int l = lane & 31, h = lane >> 5;
  const unsigned short* Trow = T + l * 2;
  float2 a = gather_node(Trow, csrSW, rowPtr[wid], rowPtr[wid + 1], lane, h);
  if (h == 0) {
    float v0 = fmaxf(a.x + bias[2 * l], 0.f);
    float v1 = fmaxf(a.y + bias[2 * l + 1], 0.f);
    ushort2 o; o.x = f2bf(v0); o.y = f2bf(v1);
    *(ushort2*)&Hout[(size_t)wid * 64 + 2 * l] = o;
  }
}

// ---- pull + bias + run-length segment-max pooling (layer 3) -----------------

__global__ __launch_bounds__(256) void pull_pool(const unsigned short* __restrict__ T,
                                                 const int* __restrict__ rowPtr,
                                                 const int2* __restrict__ csrSW,
                                                 const float* __restrict__ bias,
                                                 const void* __restrict__ bPtr,
                                                 const int* __restrict__ flag,
                                                 unsigned* __restrict__ pooled) {
  int wid = (blockIdx.x * 256 + threadIdx.x) >> 6;
  int lane = threadIdx.x & 63;
  const int n0 = wid * POOL_RUN;
  if (n0 >= N_NODES) return;
  const int l = lane & 31, h = lane >> 5;
  const unsigned short* Trow = T + l * 2;
  const int n1 = min(n0 + POOL_RUN, N_NODES);
  const float blane = bias[2 * l + h];
  int curg = load_idx(bPtr, flag, n0);
  float best = -3.4e38f;
  for (int n = n0; n < n1; ++n) {
    float2 a = gather_node(Trow, csrSW, rowPtr[n], rowPtr[n + 1], lane, h);
    float v = (h ? a.y : a.x) + blane;
    int g = load_idx(bPtr, flag, n);
    if (g != curg) {
      atomicMax(&pooled[curg * 64 + 2 * l + h], f2ord(best));
      curg = g; best = v;
    } else {
      best = fmaxf(best, v);
    }
  }
  atomicMax(&pooled[curg * 64 + 2 * l + h], f2ord(best));
}

// ---- fallback path (small ws): dense GEMM + atomic scatter ------------------

template<bool RELU_IN, bool ADD_BIAS, bool RELU_OUT>
__global__ __launch_bounds__(256) void gemm64(const float* A,
                                              const float* __restrict__ W,
                                              const float* __restrict__ b,
                                              float* C, int N) {
  __shared__ float Wt[64][68];
  __shared__ float At[64][68];
  const int tid = threadIdx.x;
  const int rowBase = blockIdx.x * 64;

  for (int i = tid; i < 4096; i += 256) {
    int k = i >> 6, c = i & 63;
    Wt[c][k] = W[i];
  }
  const float4* A4 = (const float4*)A;
  #pragma unroll
  for (int j = 0; j < 4; ++j) {
    int t4 = tid + j * 256;
    int g4 = rowBase * 16 + t4;
    float4 v = make_float4(0.f, 0.f, 0.f, 0.f);
    if (g4 < N * 16) v = A4[g4];
    if (RELU_IN) {
      v.x = fmaxf(v.x, 0.f); v.y = fmaxf(v.y, 0.f);
      v.z = fmaxf(v.z, 0.f); v.w = fmaxf(v.w, 0.f);
    }
    int r = t4 >> 4, k4 = t4 & 15;
    *(float4*)&At[r][k4 * 4] = v;
  }
  __syncthreads();

  const int c = tid & 63;
  const int r0 = (tid >> 6) * 16;
  float acc[16];
  #pragma unroll
  for (int i = 0; i < 16; ++i) acc[i] = 0.f;

  for (int k0 = 0; k0 < 64; k0 += 4) {
    float4 w = *(const float4*)&Wt[c][k0];
    #pragma unroll
    for (int i = 0; i < 16; ++i) {
      float4 a = *(const float4*)&At[r0 + i][k0];
      acc[i] += a.x * w.x + a.y * w.y + a.z * w.z + a.w * w.w;
    }
  }

  const float bias = ADD_BIAS ? b[c] : 0.f;
  #pragma unroll
  for (int i = 0; i < 16; ++i) {
    int row = rowBase + r0 + i;
    if (row < N) {
      float v = acc[i] + bias;
      if (RELU_OUT) v = fmaxf(v, 0.f);
      C[row * 64 + c] = v;
    }
  }
}

__global__ __launch_bounds__(256) void init_bias(float* __restrict__ agg,
                                                 const float* __restrict__ b, int n4) {
  int i = blockIdx.x * 256 + threadIdx.x;
  if (i >= n4) return;
  ((float4*)agg)[i] = ((const float4*)b)[i & 15];
}

__global__ __launch_bounds__(256) void scatter_add(const float* __restrict__ h,
                                                   const void* __restrict__ eiPtr,
                                                   const int* __restrict__ flag,
                                                   const float* __restrict__ ew,
                                                   float* __restrict__ agg) {
  int gtid = blockIdx.x * 256 + threadIdx.x;
  int e = gtid >> 6, lane = gtid & 63;
  if (e >= N_EDGES) return;
  int s = load_idx(eiPtr, flag, e);
  int d = load_idx(eiPtr, flag, (long long)N_EDGES + e);
  atomicAdd(&agg[d * 64 + lane], ew[e] * h[s * 64 + lane]);
}

__global__ __launch_bounds__(256) void seg_max(const float* __restrict__ h,
                                               const void* __restrict__ bPtr,
                                               const int* __restrict__ flag,
                                               unsigned* __restrict__ pooled) {
  int gtid = blockIdx.x * 256 + threadIdx.x;
  int n = gtid >> 6, lane = gtid & 63;
  if (n >= N_NODES) return;
  int g = load_idx(bPtr, flag, n);
  atomicMax(&pooled[g * 64 + lane], f2ord(h[n * 64 + lane]));
}

// ---- BatchNorm + linear head ------------------------------------------------

__global__ __launch_bounds__(256) void bn_head(const unsigned* __restrict__ pooled,
                                               const float* __restrict__ gamma,
                                               const float* __restrict__ beta,
                                               const float* __restrict__ linW,
                                               const float* __restrict__ linb,
                                               float* __restrict__ out) {
  __shared__ float P[NGRAPHS][64 + 1];
  __shared__ float mean_s[64], rstd_s[64];
  const int tid = threadIdx.x;

  for (int i = tid; i < NGRAPHS * 64; i += 256) {
    P[i >> 6][i & 63] = ord2f(pooled[i]);
  }
  __syncthreads();

  if (tid < 64) {
    float s = 0.f, ss = 0.f;
    for (int g = 0; g < NGRAPHS; ++g) {
      float v = P[g][tid];
      s += v; ss += v * v;
    }
    float m = s / (float)NGRAPHS;
    float var = ss / (float)NGRAPHS - m * m;
    mean_s[tid] = m;
    rstd_s[tid] = rsqrtf(var + BN_EPS);
  }
  __syncthreads();

  float acc = linb[0];
  #pragma unroll 8
  for (int c = 0; c < 64; ++c) {
    float normed = (P[tid][c] - mean_s[c]) * rstd_s[c] * gamma[c] + beta[c];
    acc += normed * linW[c];
  }
  out[tid] = acc;
}

// ---- launch -----------------------------------------------------------------

extern "C" void kernel_launch(void* const* d_in, const int* in_sizes, int n_in,
                              void* d_out, int out_size, void* d_ws, size_t ws_size,
                              hipStream_t stream) {
  const float* x     = (const float*)d_in[0];
  const void*  ei    = d_in[1];
  const float* ew    = (const float*)d_in[2];
  const void*  batch = d_in[3];
  const float* W1    = (const float*)d_in[4];
  const float* b1    = (const float*)d_in[5];
  const float* W2    = (const float*)d_in[6];
  const float* b2    = (const float*)d_in[7];
  const float* W3    = (const float*)d_in[8];
  const float* b3    = (const float*)d_in[9];
  const float* gamma = (const float*)d_in[10];
  const float* beta  = (const float*)d_in[11];
  const float* linW  = (const float*)d_in[12];
  const float* linb  = (const float*)d_in[13];

  char* ws = (char*)d_ws;
  const size_t MAT  = (size_t)N_NODES * 64 * sizeof(float);           // 25.6 MB
  const size_t TBL  = (size_t)N_NODES * 64 * sizeof(unsigned short);  // 12.8 MB
  const size_t CSR  = (size_t)N_EDGES * sizeof(int2);                 // 12.8 MB
  const size_t PTR  = ((size_t)(N_NODES + 1) * sizeof(int) + 255) & ~(size_t)255;

  size_t off = 0;
  unsigned short* uA = (unsigned short*)(ws + off); off += TBL;  // aliases CSR tmp
  unsigned short* hB = (unsigned short*)(ws + off); off += TBL;
  int2*  csrSW  = (int2*)(ws + off);           off += CSR;
  int*   rowPtr = (int*)(ws + off);            off += PTR;
  int*   bukCnt = (int*)(ws + off);            off += 1024;
  int*   bukBas = (int*)(ws + off);            off += 1024;
  int*   bukCur = (int*)(ws + off);            off += 1024;
  unsigned* pooled = (unsigned*)(ws + off);    off += (size_t)NGRAPHS * 64 * sizeof(unsigned);
  int*   flag   = (int*)(ws + off);            off += 256;
  const bool csrPath = (ws_size >= off);

  const int gemmBlocks = (N_NODES + 63) / 64;             // 1563
  const int nodeWaveBlocks = (N_NODES * 64) / 256;        // 25000
  const int poolBlocks = (N_NODES + POOL_RUN * 4 - 1) / (POOL_RUN * 4);  // 3125

  detect_i64<<<1, 64, 0, stream>>>((const unsigned*)ei, flag);

  if (csrPath) {
    int2* tmp = (int2*)uA;   // 12.8 MB, only live during CSR build (before gemm1)
    // ---- build CSR (bucketed counting sort) ----
    hipMemsetAsync(bukCnt, 0, 1024, stream);
    bucket_hist<<<BIN_BLOCKS, 256, 0, stream>>>(ei, flag, bukCnt);
    bucket_scan<<<1, 256, 0, stream>>>(bukCnt, bukBas, bukCur, rowPtr);
    binpass<<<BIN_BLOCKS, 256, 0, stream>>>(ei, flag, ew, bukCur, tmp);
    place2<<<NBUK, 256, 0, stream>>>(tmp, bukBas, rowPtr, csrSW);

    // ---- reference-order layers: u = h@W (gemm), then aggregate+bias(+relu) ----
    // layer 1
    gemm_u<true><<<gemmBlocks, 256, 0, stream>>>(x, W1, uA, N_NODES);
    pull_relu<<<nodeWaveBlocks, 256, 0, stream>>>(uA, rowPtr, csrSW, b1, hB);
    // layer 2
    gemm_u<false><<<gemmBlocks, 256, 0, stream>>>(hB, W2, uA, N_NODES);
    pull_relu<<<nodeWaveBlocks, 256, 0, stream>>>(uA, rowPtr, csrSW, b2, hB);
    // layer 3: gemm, then pull + bias + fused segment-max
    gemm_u<false><<<gemmBlocks, 256, 0, stream>>>(hB, W3, uA, N_NODES);
    hipMemsetAsync(pooled, 0, (size_t)NGRAPHS * 64 * sizeof(unsigned), stream);
    pull_pool<<<poolBlocks, 256, 0, stream>>>(uA, rowPtr, csrSW, b3, batch, flag, pooled);

    bn_head<<<1, 256, 0, stream>>>(pooled, gamma, beta, linW, linb, (float*)d_out);
  } else {
    // ---- fallback: atomic scatter path ----
    float* h   = (float*)ws;
    float* agg = (float*)(ws + MAT);
    unsigned* pooled2 = (unsigned*)(ws + 2 * MAT);
    int* flag2 = (int*)(ws + 2 * MAT + (size_t)NGRAPHS * 64 * sizeof(unsigned));
    detect_i64<<<1, 64, 0, stream>>>((const unsigned*)ei, flag2);
    const int n4 = N_NODES * 16;
    const int initBlocks = (n4 + 255) / 256;
    const int scatBlocks = (N_EDGES * 64) / 256;

    gemm64<false, false, false><<<gemmBlocks, 256, 0, stream>>>(x, W1, b1, h, N_NODES);
    init_bias<<<initBlocks, 256, 0, stream>>>(agg, b1, n4);
    scatter_add<<<scatBlocks, 256, 0, stream>>>(h, ei, flag2, ew, agg);
    gemm64<true, false, false><<<gemmBlocks, 256, 0, stream>>>(agg, W2, b2, h, N_NODES);
    init_bias<<<initBlocks, 256, 0, stream>>>(agg, b2, n4);
    scatter_add<<<scatBlocks, 256, 0, stream>>>(h, ei, flag2, ew, agg);
    gemm64<true, false, false><<<gemmBlocks, 256, 0, stream>>>(agg, W3, b3, h, N_NODES);
    init_bias<<<initBlocks, 256, 0, stream>>>(agg, b3, n4);
    scatter_add<<<scatBlocks, 256, 0, stream>>>(h, ei, flag2, ew, agg);

    hipMemsetAsync(pooled2, 0, (size_t)NGRAPHS * 64 * sizeof(unsigned), stream);
    seg_max<<<nodeWaveBlocks, 256, 0, stream>>>(agg, batch, flag2, pooled2);
    bn_head<<<1, 256, 0, stream>>>(pooled2, gamma, beta, linW, linb, (float*)d_out);
  }
}